// Round 1
// baseline (50.216 us; speedup 1.0000x reference)
//
#include <hip/hip_runtime.h>

#define NB 4
#define NP 6
#define NQ 4
#define NN 512
#define NWD 128
#define NBPQ (NB * NP * NQ)       // 96
#define NROWS (NBPQ * NN)         // 49152
#define ALPHA 0.2f

__device__ __forceinline__ float lrelu(float x) {
    return x > 0.f ? x : ALPHA * x;
}

// Kernel 1: Wa1[k] = sum_d W[k][d] * a1[d]; Wa2[k] = sum_d W[k][d] * a2[d]
// One block, 256 threads (t<128 -> Wa1, t>=128 -> Wa2).
__global__ void wa_kernel(const float* __restrict__ W, const float* __restrict__ a,
                          float* __restrict__ wa) {
    int t = threadIdx.x;
    int k = t & (NWD - 1);
    int half = t >> 7;                 // 0 or 1
    const float* av = a + half * NWD;  // a1 or a2
    const float* wr = W + (long)k * NWD;
    float s = 0.f;
    #pragma unroll 8
    for (int d = 0; d < NWD; ++d) s += wr[d] * av[d];
    wa[half * NWD + k] = s;
}

// Kernel 2: per global row g over (b,p,q,n): s1[g] = st_feat_row . Wa1, s2 likewise.
// Block = 256 = 4 waves; one wave per row; lane holds 2 of 128 elems.
__global__ __launch_bounds__(256) void s_kernel(const float* __restrict__ st,
                                                const float* __restrict__ wa,
                                                float* __restrict__ s1,
                                                float* __restrict__ s2) {
    int wid = threadIdx.x >> 6;
    int lane = threadIdx.x & 63;
    long g = (long)blockIdx.x * 4 + wid;   // 0 .. NROWS-1
    const float2 f  = *reinterpret_cast<const float2*>(st + g * NWD + lane * 2);
    const float2 w1 = *reinterpret_cast<const float2*>(wa + lane * 2);
    const float2 w2 = *reinterpret_cast<const float2*>(wa + NWD + lane * 2);
    float p1 = f.x * w1.x + f.y * w1.y;
    float p2 = f.x * w2.x + f.y * w2.y;
    #pragma unroll
    for (int off = 32; off > 0; off >>= 1) {
        p1 += __shfl_xor(p1, off);
        p2 += __shfl_xor(p2, off);
    }
    if (lane == 0) { s1[g] = p1; s2[g] = p2; }
}

// Kernel 3: per output row: e[j] = lrelu(s1[i]+s2[j]); softmax over j;
// out[j] = lrelu(demand[j] * att[j]).  One wave per row, 8 cols/lane (2x float4).
__global__ __launch_bounds__(256) void main_kernel(const float* __restrict__ demand,
                                                   const float* __restrict__ s1,
                                                   const float* __restrict__ s2,
                                                   float* __restrict__ out) {
    int wid = threadIdx.x >> 6;
    int lane = threadIdx.x & 63;
    long g = (long)blockIdx.x * 4 + wid;     // global row, 0 .. NROWS-1
    long slice = g >> 9;                     // (b,p,q) index
    float s1i = s1[g];
    const float* s2s = s2 + slice * NN;

    const int c0 = lane * 4;
    const int c1 = 256 + lane * 4;
    const float4 sa = *reinterpret_cast<const float4*>(s2s + c0);
    const float4 sb = *reinterpret_cast<const float4*>(s2s + c1);

    float e[8];
    e[0] = lrelu(s1i + sa.x); e[1] = lrelu(s1i + sa.y);
    e[2] = lrelu(s1i + sa.z); e[3] = lrelu(s1i + sa.w);
    e[4] = lrelu(s1i + sb.x); e[5] = lrelu(s1i + sb.y);
    e[6] = lrelu(s1i + sb.z); e[7] = lrelu(s1i + sb.w);

    // wave max over all 512 cols
    float m = e[0];
    #pragma unroll
    for (int k = 1; k < 8; ++k) m = fmaxf(m, e[k]);
    #pragma unroll
    for (int off = 32; off > 0; off >>= 1) m = fmaxf(m, __shfl_xor(m, off));

    float p[8];
    float sum = 0.f;
    #pragma unroll
    for (int k = 0; k < 8; ++k) { p[k] = expf(e[k] - m); sum += p[k]; }
    #pragma unroll
    for (int off = 32; off > 0; off >>= 1) sum += __shfl_xor(sum, off);
    const float inv = 1.f / sum;

    const float* drow = demand + g * NN;
    const float4 d0 = *reinterpret_cast<const float4*>(drow + c0);
    const float4 d1 = *reinterpret_cast<const float4*>(drow + c1);

    float4 o0, o1;
    o0.x = lrelu(d0.x * p[0] * inv); o0.y = lrelu(d0.y * p[1] * inv);
    o0.z = lrelu(d0.z * p[2] * inv); o0.w = lrelu(d0.w * p[3] * inv);
    o1.x = lrelu(d1.x * p[4] * inv); o1.y = lrelu(d1.y * p[5] * inv);
    o1.z = lrelu(d1.z * p[6] * inv); o1.w = lrelu(d1.w * p[7] * inv);

    float* orow = out + g * NN;
    *reinterpret_cast<float4*>(orow + c0) = o0;
    *reinterpret_cast<float4*>(orow + c1) = o1;
}

extern "C" void kernel_launch(void* const* d_in, const int* in_sizes, int n_in,
                              void* d_out, int out_size, void* d_ws, size_t ws_size,
                              hipStream_t stream) {
    const float* demand  = (const float*)d_in[0];
    const float* st_feat = (const float*)d_in[1];
    const float* W       = (const float*)d_in[2];
    const float* a       = (const float*)d_in[3];
    float* out = (float*)d_out;

    float* wa = (float*)d_ws;                  // 256 floats
    float* s1 = wa + 2 * NWD;                  // NROWS floats
    float* s2 = s1 + NROWS;                    // NROWS floats

    wa_kernel<<<1, 256, 0, stream>>>(W, a, wa);
    s_kernel<<<NROWS / 4, 256, 0, stream>>>(st_feat, wa, s1, s2);
    main_kernel<<<NROWS / 4, 256, 0, stream>>>(demand, s1, s2, out);
}